// Round 7
// baseline (197.323 us; speedup 1.0000x reference)
//
#include <hip/hip_runtime.h>
#include <math.h>

// ROUND-7: fault-proof full-numerics probe.
// R6's zero-writer aborted => either any-dispatch-environment failure, or
// out_size vs actual allocation are inconsistent (e.g. out_size counts
// complex64 elements but the buffer was allocated as out_size float32s).
// This kernel caps ALL stores at the minimal allocation implied by ANY
// bookkeeping: cap_bytes = out_size * (bytes-matched ? 1 : 4). That bound
// is <= the real allocation in every consistent AND inconsistent scenario,
// so a GPU page fault from this kernel is impossible.

#define F_MSUN   ((float)1.9884099021470415e30)
#define F_G      ((float)6.67430e-11)
#define F_PI     ((float)3.14159265358979323846)
#define F_C      ((float)299792458.0)
#define F_C3     ((float)(299792458.0*299792458.0*299792458.0))
#define F_PIG    ((float)(3.14159265358979323846*6.67430e-11))
#define F_5G     ((float)(5.0*6.67430e-11))
#define F_6_15   ((float)14.696938456699069)              /* 6.0**1.5 */
#define F_743    ((float)(743.0/252.0))
#define F_226    ((float)(226.0/15.0))
#define F_32PI5  ((float)(32.0*3.14159265358979323846/5.0))
#define F_BIG    ((float)(3058673.0/508032.0))
#define F_THIRD  ((float)(1.0/3.0))
#define F_56     ((float)(5.0/6.0))
#define F_M76    ((float)(-7.0/6.0))

__global__ void cbc_flat_kernel(
        const float* __restrict__ mass1,
        const float* __restrict__ mass2,
        const float* __restrict__ s1z,
        const float* __restrict__ s2z,
        const float* __restrict__ dist,
        const float* __restrict__ incl,
        float2* __restrict__ out,
        unsigned long long lim_f2,         // floor(cap_bytes/8): hard store bound
        unsigned long long half,           // B*F
        int F, float dff, float apsf) {
    unsigned long long g = (unsigned long long)blockIdx.x * 256ull
                         + (unsigned long long)threadIdx.x;
    if (g >= lim_f2) return;               // provably within allocation

    int isplus = (g >= half) ? 1 : 0;
    unsigned long long e = isplus ? (g - half) : g;
    int r = (int)(e / (unsigned long long)F);
    int k = (int)(e - (unsigned long long)r * (unsigned long long)F);

    // ---- per-row constants (consecutive g share r -> wave-mostly-uniform) ----
    float m1 = mass1[r] * F_MSUN;           // f32, like jnp
    float m2 = mass2[r] * F_MSUN;
    float s1 = s1z[r], s2 = s2z[r];
    float M  = m1 + m2;

    float fisco = F_C3 / (((F_G * M) * F_PI) * F_6_15);
    float f_min = fminf(fisco, 20.0f);

    float nu  = (m1 * m2) / (M * M);
    float as1 = fabsf(s1), as2 = fabsf(s2);
    float chi = (as1 > as2) ? as1 : as2;
    float c0  = ((5.0f * M) * F_G) / ((256.0f * nu) * F_C3);
    float cc2 = F_743 + ((11.0f * nu) / 3.0f);
    float cc3 = F_226 * chi - F_32PI5;
    float cc4 = (F_BIG + ((5429.0f * nu) / 504.0f)) + (((617.0f * nu) * nu) / 72.0f);
    float vv  = powf((F_PIG * M) * f_min, F_THIRD) / F_C;
    float x2 = vv * vv, x4 = x2 * x2, x8 = x4 * x4;        // XLA integer_pow(-8)
    float vm8 = 1.0f / x8;
    float poly = 1.0f + ((cc2 + ((cc3 + (cc4 * vv)) * vv)) * vv) * vv;
    float tchirp = (c0 * vm8) * poly;

    float c0b  = (F_5G * M) / ((256.0f * nu) * F_C3);
    float targ = 1.1f * tchirp;
    float fstart = (powf(c0b / targ, 0.375f) * F_C3) / (F_PIG * M);

    float eta = nu;
    float mc  = powf(eta, 0.6f) * M;
    float p56 = powf((F_G * mc) / F_C3, F_56);
    float CdD = F_C / dist[r];
    float ci  = cosf(incl[r]);
    float pfac = 0.5f * (1.0f + ci * ci);

    float k0f = rintf(fstart / dff);                       // jnp.round = half-even
    float k1f = rintf(f_min / dff);
    float denf = fmaxf(k1f - k0f, 1.0f);

    // ---- per-column ----
    float kf = (float)k;
    float fk = kf * dff;                                   // exact (df = 2^-n)
    float2 o = make_float2(0.0f, 0.0f);

    if (k != F - 1 && fk >= fstart) {
        float t  = ((F_PIG * M) * fk) / F_C3;
        float v  = powf(t, F_THIRD);
        float v2 = v * v, v4 = v2 * v2, v5 = v4 * v;       // XLA integer_pow(5)
        float phase = 3.0f / ((128.0f * eta) * v5);
        float sp = sinf(phase), cp = cosf(phase);
        float ampcol = powf(fk, F_M76);
        float amp = (p56 * ampcol) * CdD;
        float hre = amp * cp;
        float him = amp * (-sp);                           // amp*sin(-phase)

        float re, im;
        if (isplus) { re = hre * pfac;  im = him * pfac; } // plus = h*pfac
        else        { re = him * ci;    im = (-hre) * ci; }// cross = -1j*h*ci

        float sc = 1.0f;                                   // taper window
        if (kf >= k0f && kf <= k1f)
            sc = 0.5f - 0.5f * cosf((F_PI * (kf - k0f)) / denf);
        re *= sc; im *= sc;

        float ang = apsf * kf;                             // phase shift
        float c2c = cosf(ang), s2c = sinf(ang);
        o.x = re * c2c - im * s2c;
        o.y = re * s2c + im * c2c;
    }
    out[g] = o;
}

extern "C" void kernel_launch(void* const* d_in, const int* in_sizes, int n_in,
                              void* d_out, int out_size, void* d_ws, size_t ws_size,
                              hipStream_t stream) {
    (void)d_ws; (void)ws_size;
    if (!d_in || !d_out || !in_sizes || n_in < 6 || out_size <= 0) return;
    const float* mass1 = (const float*)d_in[0];
    const float* mass2 = (const float*)d_in[1];
    const float* s1z   = (const float*)d_in[2];
    const float* s2z   = (const float*)d_in[3];
    const float* dist  = (const float*)d_in[4];
    const float* incl  = (const float*)d_in[5];
    if (!mass1 || !mass2 || !s1z || !s2z || !dist || !incl) return;
    long B = (long)in_sizes[0];
    if (B < 1 || B > (1L << 20)) return;

    // F inference (same as R2-R6; it demonstrably matches and launches):
    // out_size as float count (4BF), complex count (2BF), byte count (16BF),
    // f32-pair count (8BF); F-1 pow2 & F odd make these mutually exclusive.
    auto ispow2 = [](long x) { return x > 0 && ((x & (x - 1)) == 0); };
    long F = 0; long matched_den = 0;
    const long dens[4] = {4, 2, 16, 8};
    for (int i = 0; i < 4 && F == 0; ++i) {
        long d = dens[i] * B;
        long cand = (long)out_size / d;
        if (cand > 1 && cand * d == (long)out_size && ispow2(cand - 1)) {
            F = cand; matched_den = dens[i];
        }
    }
    if (F == 0) return;

    // Minimal-allocation cap: if out_size matched as a BYTE count the
    // allocation is at least out_size bytes; otherwise out_size counts
    // elements and the smallest element branch is float32 (4 B). This is a
    // lower bound on the true allocation under every consistent AND
    // inconsistent bookkeeping scenario -> stores can never fault.
    unsigned long long cap_bytes = (unsigned long long)out_size
                                 * (matched_den == 16 ? 1ull : 4ull);
    unsigned long long lim_f2 = cap_bytes / 8ull;

    unsigned long long half  = (unsigned long long)B * (unsigned long long)F;
    unsigned long long total = 2ull * half;
    if (lim_f2 > total) lim_f2 = total;
    if (lim_f2 == 0) return;

    double df = 1024.0 / (double)(F - 1);                  // SAMPLE_RATE/chirplen_max
    float dff = (float)df;
    float apsf = (float)(2.0 * 3.14159265358979323846 * df * 0.5);

    unsigned long long nblocks = (lim_f2 + 255ull) / 256ull;
    cbc_flat_kernel<<<dim3((unsigned)nblocks), dim3(256), 0, stream>>>(
        mass1, mass2, s1z, s2z, dist, incl,
        (float2*)d_out, lim_f2, half, (int)F, dff, apsf);
}

// Round 8
// 89.946 us; speedup vs baseline: 2.1938x; 2.1938x over previous
//
#include <hip/hip_runtime.h>
#include <math.h>

// Measured harness facts (R7, absmax=0.0):
//   out_size = 2*B*F float32s; allocation = out_size*4 bytes = one [B,F]
//   complex64 array; validated output is hc ONLY (cross polarization).
//   F-1 pow2 (F=32769 at B=256). Writing beyond B*F float2s page-faults.
// Numerics below are bit-exact vs the jax/XLA reference (absmax 0.0) — do
// not reorder float ops.

#define F_MSUN   ((float)1.9884099021470415e30)
#define F_G      ((float)6.67430e-11)
#define F_PI     ((float)3.14159265358979323846)
#define F_C      ((float)299792458.0)
#define F_C3     ((float)(299792458.0*299792458.0*299792458.0))
#define F_PIG    ((float)(3.14159265358979323846*6.67430e-11))
#define F_5G     ((float)(5.0*6.67430e-11))
#define F_6_15   ((float)14.696938456699069)              /* 6.0**1.5 */
#define F_743    ((float)(743.0/252.0))
#define F_226    ((float)(226.0/15.0))
#define F_32PI5  ((float)(32.0*3.14159265358979323846/5.0))
#define F_BIG    ((float)(3058673.0/508032.0))
#define F_THIRD  ((float)(1.0/3.0))
#define F_56     ((float)(5.0/6.0))
#define F_M76    ((float)(-7.0/6.0))

#define ROWS_PER_BLOCK 32
// per-row LDS record:
//  0:A(=PIG*M) 1:E(=128*eta) 2:p56 3:CdD 4:ci 5:fstart 6:k0f 7:k1f 8:denf
#define RC_STRIDE 9

__global__ __launch_bounds__(256) void cbc_kernel(
        const float* __restrict__ mass1,
        const float* __restrict__ mass2,
        const float* __restrict__ s1z,
        const float* __restrict__ s2z,
        const float* __restrict__ dist,
        const float* __restrict__ incl,
        float2* __restrict__ out,
        unsigned long long lim_f2,         // hard store bound (float2 units)
        int B, int F, float dff, float apsf) {
    __shared__ float srow[ROWS_PER_BLOCK * RC_STRIDE];

    int r0 = (int)blockIdx.y * ROWS_PER_BLOCK;

    if (threadIdx.x < ROWS_PER_BLOCK) {
        int r = r0 + (int)threadIdx.x;
        if (r < B) {
            float m1 = mass1[r] * F_MSUN;           // f32, like jnp
            float m2 = mass2[r] * F_MSUN;
            float s1 = s1z[r], s2 = s2z[r];
            float M  = m1 + m2;

            float fisco = F_C3 / (((F_G * M) * F_PI) * F_6_15);
            float f_min = fminf(fisco, 20.0f);

            float nu  = (m1 * m2) / (M * M);
            float as1 = fabsf(s1), as2 = fabsf(s2);
            float chi = (as1 > as2) ? as1 : as2;
            float c0  = ((5.0f * M) * F_G) / ((256.0f * nu) * F_C3);
            float cc2 = F_743 + ((11.0f * nu) / 3.0f);
            float cc3 = F_226 * chi - F_32PI5;
            float cc4 = (F_BIG + ((5429.0f * nu) / 504.0f)) + (((617.0f * nu) * nu) / 72.0f);
            float vv  = powf((F_PIG * M) * f_min, F_THIRD) / F_C;
            float x2 = vv * vv, x4 = x2 * x2, x8 = x4 * x4;   // XLA integer_pow(-8)
            float vm8 = 1.0f / x8;
            float poly = 1.0f + ((cc2 + ((cc3 + (cc4 * vv)) * vv)) * vv) * vv;
            float tchirp = (c0 * vm8) * poly;

            float c0b  = (F_5G * M) / ((256.0f * nu) * F_C3);
            float targ = 1.1f * tchirp;
            float fstart = (powf(c0b / targ, 0.375f) * F_C3) / (F_PIG * M);

            float eta = nu;
            float mc  = powf(eta, 0.6f) * M;
            float p56 = powf((F_G * mc) / F_C3, F_56);
            float CdD = F_C / dist[r];
            float ci  = cosf(incl[r]);

            float k0f = rintf(fstart / dff);               // jnp.round = half-even
            float k1f = rintf(f_min / dff);
            float denf = fmaxf(k1f - k0f, 1.0f);

            float* o = srow + (int)threadIdx.x * RC_STRIDE;
            o[0] = F_PIG * M;  o[1] = 128.0f * eta;  o[2] = p56;
            o[3] = CdD;        o[4] = ci;            o[5] = fstart;
            o[6] = k0f;        o[7] = k1f;           o[8] = denf;
        }
    }
    __syncthreads();

    int k = (int)blockIdx.x * 256 + (int)threadIdx.x;
    if (k >= F) return;
    float kf = (float)k;
    float fk = kf * dff;                                   // exact (df = 2^-5)

    // column constants, reused across the 32 rows this thread handles
    float ampcol = powf(fk, F_M76);                        // inf at k=0; masked there
    float ang = apsf * kf;
    float c2c = cosf(ang), s2c = sinf(ang);
    bool nyq = (k == F - 1);

    int r1 = r0 + ROWS_PER_BLOCK; if (r1 > B) r1 = B;

    for (int r = r0; r < r1; ++r) {
        const float* o = srow + (r - r0) * RC_STRIDE;      // broadcast (no conflicts)
        float A = o[0], E = o[1], p56 = o[2], CdD = o[3];
        float ci = o[4], fstart = o[5], k0f = o[6];
        float k1f = o[7], denf = o[8];

        float2 ohc = make_float2(0.0f, 0.0f);

        if (!nyq && fk >= fstart) {
            float t  = (A * fk) / F_C3;
            float v  = powf(t, F_THIRD);
            float v2 = v * v, v4 = v2 * v2, v5 = v4 * v;   // XLA integer_pow(5)
            float phase = 3.0f / (E * v5);
            float sp = sinf(phase), cp = cosf(phase);
            float amp = (p56 * ampcol) * CdD;
            float hre = amp * cp;
            float him = amp * (-sp);                       // amp*sin(-phase)
            // cross = -1j*h*cosi
            float re = him * ci;
            float im = (-hre) * ci;
            float sc = 1.0f;                               // taper window
            if (kf >= k0f && kf <= k1f)
                sc = 0.5f - 0.5f * cosf((F_PI * (kf - k0f)) / denf);
            re *= sc; im *= sc;
            // phase shift: (re+i*im)*(c2c+i*s2c)
            ohc.x = re * c2c - im * s2c;
            ohc.y = re * s2c + im * c2c;
        }
        unsigned long long idx = (unsigned long long)r * (unsigned long long)F
                               + (unsigned long long)k;
        if (idx < lim_f2) out[idx] = ohc;                  // provably in-bounds
    }
}

extern "C" void kernel_launch(void* const* d_in, const int* in_sizes, int n_in,
                              void* d_out, int out_size, void* d_ws, size_t ws_size,
                              hipStream_t stream) {
    (void)d_ws; (void)ws_size;
    if (!d_in || !d_out || !in_sizes || n_in < 6 || out_size <= 0) return;
    const float* mass1 = (const float*)d_in[0];
    const float* mass2 = (const float*)d_in[1];
    const float* s1z   = (const float*)d_in[2];
    const float* s2z   = (const float*)d_in[3];
    const float* dist  = (const float*)d_in[4];
    const float* incl  = (const float*)d_in[5];
    if (!mass1 || !mass2 || !s1z || !s2z || !dist || !incl) return;
    long B = (long)in_sizes[0];
    if (B < 1 || B > (1L << 20)) return;

    // Measured: out_size = 2*B*F float32s (den=2 match), allocation =
    // out_size*4 bytes = B*F complex64 = hc only. Keep the general scan for
    // robustness; F-1 pow2 & F odd make the candidates mutually exclusive.
    auto ispow2 = [](long x) { return x > 0 && ((x & (x - 1)) == 0); };
    long F = 0; long matched_den = 0;
    const long dens[4] = {2, 4, 16, 8};
    for (int i = 0; i < 4 && F == 0; ++i) {
        long d = dens[i] * B;
        long cand = (long)out_size / d;
        if (cand > 1 && cand * d == (long)out_size && ispow2(cand - 1)) {
            F = cand; matched_den = dens[i];
        }
    }
    if (F == 0) return;

    // Minimal-allocation cap (cannot fault under any bookkeeping): byte-match
    // -> out_size bytes; element-match -> out_size * 4 bytes.
    unsigned long long cap_bytes = (unsigned long long)out_size
                                 * (matched_den == 16 ? 1ull : 4ull);
    unsigned long long lim_f2 = cap_bytes / 8ull;
    unsigned long long half = (unsigned long long)B * (unsigned long long)F;
    if (lim_f2 > half) lim_f2 = half;                      // hc only (measured)
    if (lim_f2 == 0) return;

    double df = 1024.0 / (double)(F - 1);                  // SAMPLE_RATE/chirplen_max
    float dff = (float)df;
    float apsf = (float)(2.0 * 3.14159265358979323846 * df * 0.5);

    dim3 grid((unsigned)((F + 255) / 256),
              (unsigned)((B + ROWS_PER_BLOCK - 1) / ROWS_PER_BLOCK));
    cbc_kernel<<<grid, dim3(256), 0, stream>>>(
        mass1, mass2, s1z, s2z, dist, incl,
        (float2*)d_out, lim_f2, (int)B, (int)F, dff, apsf);
}